// Round 1
// baseline (1143.888 us; speedup 1.0000x reference)
//
#include <hip/hip_runtime.h>
#include <math.h>

#define N_NODES 16384
#define TI 8                 // rows per adjacency block: full-row contiguous stripes
#define NCH (N_NODES / 4)    // float4 chunks per row = 4096

typedef float vf4 __attribute__((ext_vector_type(4)));

// ---------------------------------------------------------------------------
// MLP: out[i] = silu(emb[z[i]] @ w1 + b1) @ w2 + b2
// One wave (64 lanes) per node; lane j owns column j of w1 (128x64).
//
// Block 0 additionally:
//  (a) detects whether `batch` is int64 (jax x64) or int32: batch is sorted
//      non-decreasing in [0,64). Read as int32: the int32 case never
//      decreases; the int64 case interleaves zeros -> decreases appear.
//      ws[0] = flag (0 = int32, 1 = int64).
//  (b) builds a batch-CSR: ws[1+v] = first index j with batch[j] >= v, for
//      v = 0..64 (so ws[65] == N). Because batch is sorted, the columns that
//      can possibly be nonzero for a row with batch value b form exactly the
//      contiguous range [ws[1+b], ws[2+b]).
// Consumed by adj_kernel (same stream => ordered, visible at kernel boundary).
// ---------------------------------------------------------------------------
__global__ __launch_bounds__(256) void mlp_kernel(const int* __restrict__ z,
                                                  const float* __restrict__ emb,
                                                  const float* __restrict__ w1,
                                                  const float* __restrict__ b1,
                                                  const float* __restrict__ w2,
                                                  const float* __restrict__ b2,
                                                  const int* __restrict__ batch32,
                                                  int* __restrict__ ws,
                                                  float* __restrict__ out) {
    if (blockIdx.x == 0) {
        __shared__ int dec;
        if (threadIdx.x == 0) dec = 0;
        __syncthreads();
        int local = 0;
        for (int k = threadIdx.x; k < N_NODES - 1; k += 256)
            if (batch32[k + 1] < batch32[k]) local = 1;
        if (local) atomicOr(&dec, 1);
        __syncthreads();
        const bool is64 = (dec != 0);
        const long long* b64v = (const long long*)batch32;
        // CSR offsets: ws[1+v] = lower_bound(batch, v), v in [0, 64]
        if (threadIdx.x < 65) {
            const int v = threadIdx.x;
            int lo = 0, hi = N_NODES;
            while (lo < hi) {
                int mid = (lo + hi) >> 1;
                int bm = is64 ? (int)b64v[mid] : batch32[mid];
                if (bm < v) lo = mid + 1; else hi = mid;
            }
            ws[1 + v] = lo;
        }
        if (threadIdx.x == 0) ws[0] = dec;
    }

    const int lane = threadIdx.x & 63;
    const int wave = threadIdx.x >> 6;
    const int i = blockIdx.x * 4 + wave;
    if (i >= N_NODES) return;

    const float4* erow = (const float4*)(emb + (size_t)z[i] * 128);
    float acc = b1[lane];
#pragma unroll 8
    for (int k4 = 0; k4 < 32; k4++) {
        float4 e = erow[k4];
        int k = k4 * 4;
        acc = fmaf(e.x, w1[(k + 0) * 64 + lane], acc);
        acc = fmaf(e.y, w1[(k + 1) * 64 + lane], acc);
        acc = fmaf(e.z, w1[(k + 2) * 64 + lane], acc);
        acc = fmaf(e.w, w1[(k + 3) * 64 + lane], acc);
    }
    float h = acc / (1.0f + expf(-acc));   // silu
    float t = h * w2[lane];
#pragma unroll
    for (int off = 32; off >= 1; off >>= 1)
        t += __shfl_xor(t, off, 64);
    if (lane == 0) out[i] = t + b2[0];
}

// ---------------------------------------------------------------------------
// Adjacency: adj[i,j] = (d2 < 64) && (batch[i]==batch[j]) && (i != j), as
// 1.0f/0.0f.
//
// Each block owns TI=8 FULL rows (512 KB contiguous). batch sorted =>
// nonzero candidates for the stripe are exactly columns [jlo, jhi) where
//   jlo = ws[1 + batch[i0]], jhi = ws[2 + batch[i0+TI-1]]   (two loads).
// Everything else is streamed as sequential nontemporal zero-float4s — the
// identical access pattern to the 6.1 TB/s rocclr fill kernel (no 64 KB
// strided walks, no per-tile classification). The compute window is
// typically 1-3 batches (~256-768 cols), ~2-5% of the matrix.
//
// COMPUTE math replicates numpy f32 semantics EXACTLY (unchanged from the
// absmax=0 kernel):
//   sq[i]  = rn(rn(x*x + y*y) + z*z)            (elementwise mul, pairwise add)
//   dot    = fma(z,z', fma(y,y', rn(x*x')))     (BLAS sgemm sequential-FMA)
//   d2     = rn(rn(sq_i + sq_j) - 2*dot)
// ---------------------------------------------------------------------------
__global__ __launch_bounds__(256) void adj_kernel(const float* __restrict__ pos,
                                                  const void* __restrict__ batch_raw,
                                                  const int* __restrict__ ws,
                                                  float* __restrict__ adj) {
    __shared__ vf4 s_p[TI];
    __shared__ int s_b[TI];

    const bool is64 = (ws[0] != 0);
    const int* b32 = (const int*)batch_raw;
    const long long* b64 = (const long long*)batch_raw;

    const int t  = threadIdx.x;
    const int i0 = blockIdx.x * TI;

    const int b_lo = is64 ? (int)b64[i0] : b32[i0];
    const int b_hi = is64 ? (int)b64[i0 + TI - 1] : b32[i0 + TI - 1];

    const int jlo = ws[1 + b_lo];   // first col with batch >= b_lo
    const int jhi = ws[2 + b_hi];   // first col with batch >  b_hi
    const int clo = jlo >> 2;               // first compute chunk
    const int chi = (jhi + 3) >> 2;         // one past last compute chunk
    // chunks [0,clo) and [chi,NCH): batch[j] outside [b_lo,b_hi] -> all zero.
    // chunks [clo,chi): compute (cols widened into the window get 0 via the
    // batch-equality check, so coverage is exact and write-once).

    if (t < TI) {
        const int i = i0 + t;
        float x = pos[i * 3 + 0], y = pos[i * 3 + 1], z = pos[i * 3 + 2];
        vf4 p;
        p.x = x; p.y = y; p.z = z;
        p.w = __fadd_rn(__fadd_rn(__fmul_rn(x, x), __fmul_rn(y, y)), __fmul_rn(z, z));
        s_p[t] = p;
        s_b[t] = is64 ? (int)b64[i] : b32[i];
    }
    __syncthreads();

    // --- Zero streams: per row, two sequential runs (fill-kernel pattern) ---
    const vf4 zero = {0.0f, 0.0f, 0.0f, 0.0f};
#pragma unroll
    for (int r = 0; r < TI; r++) {
        vf4* row4 = (vf4*)(adj + (size_t)(i0 + r) * N_NODES);
        for (int c = t; c < clo; c += 256)
            __builtin_nontemporal_store(zero, row4 + c);
        for (int c = chi + t; c < NCH; c += 256)
            __builtin_nontemporal_store(zero, row4 + c);
    }

    // --- Compute window ---
    for (int c = clo + t; c < chi; c += 256) {
        const int j0 = c * 4;
        // 4 consecutive j: 12 contiguous floats -> 3 aligned float4 loads.
        const float4* p4 = (const float4*)pos;
        float4 A = p4[c * 3 + 0];
        float4 B = p4[c * 3 + 1];
        float4 C = p4[c * 3 + 2];
        const float xj[4] = {A.x, A.w, B.z, C.y};
        const float yj[4] = {A.y, B.x, B.w, C.z};
        const float zj[4] = {A.z, B.y, C.x, C.w};

        float sqj[4];
#pragma unroll
        for (int m = 0; m < 4; m++)
            sqj[m] = __fadd_rn(__fadd_rn(__fmul_rn(xj[m], xj[m]), __fmul_rn(yj[m], yj[m])),
                               __fmul_rn(zj[m], zj[m]));

        int bj[4];
        if (is64) {
#pragma unroll
            for (int m = 0; m < 4; m++) bj[m] = (int)b64[j0 + m];
        } else {
            int4 bb = *(const int4*)(b32 + j0);
            bj[0] = bb.x; bj[1] = bb.y; bj[2] = bb.z; bj[3] = bb.w;
        }

#pragma unroll
        for (int r = 0; r < TI; r++) {
            vf4 p = s_p[r];
            const float xi = p.x, yi = p.y, zi = p.z, sqi = p.w;
            const int bi = s_b[r];
            float rr[4];
#pragma unroll
            for (int m = 0; m < 4; m++) {
                float dot = fmaf(zi, zj[m], fmaf(yi, yj[m], __fmul_rn(xi, xj[m])));
                float d2 = __fsub_rn(__fadd_rn(sqi, sqj[m]), __fadd_rn(dot, dot));
                bool v = (d2 < 64.0f) && (bi == bj[m]) && ((i0 + r) != (j0 + m));
                rr[m] = v ? 1.0f : 0.0f;
            }
            vf4 rv = {rr[0], rr[1], rr[2], rr[3]};
            __builtin_nontemporal_store(rv, (vf4*)(adj + (size_t)(i0 + r) * N_NODES + j0));
        }
    }
}

extern "C" void kernel_launch(void* const* d_in, const int* in_sizes, int n_in,
                              void* d_out, int out_size, void* d_ws, size_t ws_size,
                              hipStream_t stream) {
    const int*   z     = (const int*)d_in[0];
    const void*  batch = d_in[1];           // int32 or int64, detected at runtime
    const float* pos   = (const float*)d_in[2];
    const float* emb   = (const float*)d_in[3];
    const float* w1    = (const float*)d_in[4];
    const float* b1    = (const float*)d_in[5];
    const float* w2    = (const float*)d_in[6];
    const float* b2    = (const float*)d_in[7];

    float* out = (float*)d_out;             // [16384] node outputs
    float* adj = out + N_NODES;             // [16384 x 16384] adjacency as 0/1 floats
    int* ws = (int*)d_ws;                   // ws[0]=dtype flag, ws[1..65]=batch CSR

    mlp_kernel<<<N_NODES / 4, 256, 0, stream>>>(z, emb, w1, b1, w2, b2,
                                                (const int*)batch, ws, out);
    adj_kernel<<<N_NODES / TI, 256, 0, stream>>>(pos, batch, ws, adj);
}

// Round 2
// 1137.712 us; speedup vs baseline: 1.0054x; 1.0054x over previous
//
#include <hip/hip_runtime.h>
#include <math.h>

#define N_NODES 16384
#define TI 8                 // rows per window-compute block (one batch-window stripe)
#define NCH (N_NODES / 4)    // float4 chunks per row = 4096

typedef float vf4 __attribute__((ext_vector_type(4)));

// ---------------------------------------------------------------------------
// MLP: out[i] = silu(emb[z[i]] @ w1 + b1) @ w2 + b2
// One wave (64 lanes) per node; lane j owns column j of w1 (128x64).
//
// Block 0 additionally:
//  (a) detects whether `batch` is int64 (jax x64) or int32: batch is sorted
//      non-decreasing in [0,64). Read as int32: the int32 case never
//      decreases; the int64 case interleaves zeros -> decreases appear.
//      ws[0] = flag (0 = int32, 1 = int64).
//  (b) builds a batch-CSR: ws[1+v] = first index j with batch[j] >= v, for
//      v = 0..64 (so ws[65] == N). Sorted batch => the candidate columns for
//      a row with batch value b are exactly [ws[1+b], ws[2+b]).
// Consumed by window_kernel (same stream => ordered at kernel boundary).
// ---------------------------------------------------------------------------
__global__ __launch_bounds__(256) void mlp_kernel(const int* __restrict__ z,
                                                  const float* __restrict__ emb,
                                                  const float* __restrict__ w1,
                                                  const float* __restrict__ b1,
                                                  const float* __restrict__ w2,
                                                  const float* __restrict__ b2,
                                                  const int* __restrict__ batch32,
                                                  int* __restrict__ ws,
                                                  float* __restrict__ out) {
    if (blockIdx.x == 0) {
        __shared__ int dec;
        if (threadIdx.x == 0) dec = 0;
        __syncthreads();
        int local = 0;
        for (int k = threadIdx.x; k < N_NODES - 1; k += 256)
            if (batch32[k + 1] < batch32[k]) local = 1;
        if (local) atomicOr(&dec, 1);
        __syncthreads();
        const bool is64 = (dec != 0);
        const long long* b64v = (const long long*)batch32;
        if (threadIdx.x < 65) {
            const int v = threadIdx.x;
            int lo = 0, hi = N_NODES;
            while (lo < hi) {
                int mid = (lo + hi) >> 1;
                int bm = is64 ? (int)b64v[mid] : batch32[mid];
                if (bm < v) lo = mid + 1; else hi = mid;
            }
            ws[1 + v] = lo;
        }
        if (threadIdx.x == 0) ws[0] = dec;
    }

    const int lane = threadIdx.x & 63;
    const int wave = threadIdx.x >> 6;
    const int i = blockIdx.x * 4 + wave;
    if (i >= N_NODES) return;

    const float4* erow = (const float4*)(emb + (size_t)z[i] * 128);
    float acc = b1[lane];
#pragma unroll 8
    for (int k4 = 0; k4 < 32; k4++) {
        float4 e = erow[k4];
        int k = k4 * 4;
        acc = fmaf(e.x, w1[(k + 0) * 64 + lane], acc);
        acc = fmaf(e.y, w1[(k + 1) * 64 + lane], acc);
        acc = fmaf(e.z, w1[(k + 2) * 64 + lane], acc);
        acc = fmaf(e.w, w1[(k + 3) * 64 + lane], acc);
    }
    float h = acc / (1.0f + expf(-acc));   // silu
    float t = h * w2[lane];
#pragma unroll
    for (int off = 32; off >= 1; off >>= 1)
        t += __shfl_xor(t, off, 64);
    if (lane == 0) out[i] = t + b2[0];
}

// ---------------------------------------------------------------------------
// Zero pass: EXACT clone of the 6.1 TB/s rocclr fillBufferAligned access
// pattern — flat grid-stride, plain (cached, NOT nontemporal) dwordx4
// stores, no per-row structure, no dynamic bounds, no LDS, no syncs.
// Writes the entire adj buffer (1.074 GB). The ~1.6% candidate window is
// overwritten afterwards by window_kernel (extra ~17 MB, negligible).
// ---------------------------------------------------------------------------
#define ZBLOCKS 2048
__global__ __launch_bounds__(256) void zero_kernel(float* __restrict__ adj) {
    vf4* a4 = (vf4*)adj;
    const size_t total = (size_t)N_NODES * (N_NODES / 4);
    const vf4 zero = {0.0f, 0.0f, 0.0f, 0.0f};
    for (size_t idx = (size_t)blockIdx.x * 256 + threadIdx.x; idx < total;
         idx += (size_t)ZBLOCKS * 256)
        a4[idx] = zero;
}

// ---------------------------------------------------------------------------
// Window pass: adj[i,j] = (d2 < 64) && (batch[i]==batch[j]) && (i != j).
// Each block owns TI=8 rows. batch sorted => candidates are exactly columns
// [ws[1+batch[i0]], ws[2+batch[i0+TI-1]]) — typically one ~256-col batch.
// Only those chunks are written (everything else already zeroed). Columns
// widened into the chunk window get 0 via the batch-equality check, so the
// overwrite is exact.
//
// d2 replicates numpy f32 semantics EXACTLY (unchanged from absmax=0 kernel):
//   sq[i]  = rn(rn(x*x + y*y) + z*z)            (elementwise mul, pairwise add)
//   dot    = fma(z,z', fma(y,y', rn(x*x')))     (BLAS sgemm sequential-FMA)
//   d2     = rn(rn(sq_i + sq_j) - 2*dot)
// ---------------------------------------------------------------------------
__global__ __launch_bounds__(256) void window_kernel(const float* __restrict__ pos,
                                                     const void* __restrict__ batch_raw,
                                                     const int* __restrict__ ws,
                                                     float* __restrict__ adj) {
    __shared__ vf4 s_p[TI];
    __shared__ int s_b[TI];

    const bool is64 = (ws[0] != 0);
    const int* b32 = (const int*)batch_raw;
    const long long* b64 = (const long long*)batch_raw;

    const int t  = threadIdx.x;
    const int i0 = blockIdx.x * TI;

    const int b_lo = is64 ? (int)b64[i0] : b32[i0];
    const int b_hi = is64 ? (int)b64[i0 + TI - 1] : b32[i0 + TI - 1];

    const int jlo = ws[1 + b_lo];   // first col with batch >= b_lo
    const int jhi = ws[2 + b_hi];   // first col with batch >  b_hi
    const int clo = jlo >> 2;
    const int chi = (jhi + 3) >> 2;

    if (t < TI) {
        const int i = i0 + t;
        float x = pos[i * 3 + 0], y = pos[i * 3 + 1], z = pos[i * 3 + 2];
        vf4 p;
        p.x = x; p.y = y; p.z = z;
        p.w = __fadd_rn(__fadd_rn(__fmul_rn(x, x), __fmul_rn(y, y)), __fmul_rn(z, z));
        s_p[t] = p;
        s_b[t] = is64 ? (int)b64[i] : b32[i];
    }
    __syncthreads();

    for (int c = clo + t; c < chi; c += 256) {
        const int j0 = c * 4;
        // 4 consecutive j: 12 contiguous floats -> 3 aligned float4 loads.
        const float4* p4 = (const float4*)pos;
        float4 A = p4[c * 3 + 0];
        float4 B = p4[c * 3 + 1];
        float4 C = p4[c * 3 + 2];
        const float xj[4] = {A.x, A.w, B.z, C.y};
        const float yj[4] = {A.y, B.x, B.w, C.z};
        const float zj[4] = {A.z, B.y, C.x, C.w};

        float sqj[4];
#pragma unroll
        for (int m = 0; m < 4; m++)
            sqj[m] = __fadd_rn(__fadd_rn(__fmul_rn(xj[m], xj[m]), __fmul_rn(yj[m], yj[m])),
                               __fmul_rn(zj[m], zj[m]));

        int bj[4];
        if (is64) {
#pragma unroll
            for (int m = 0; m < 4; m++) bj[m] = (int)b64[j0 + m];
        } else {
            int4 bb = *(const int4*)(b32 + j0);
            bj[0] = bb.x; bj[1] = bb.y; bj[2] = bb.z; bj[3] = bb.w;
        }

#pragma unroll
        for (int r = 0; r < TI; r++) {
            vf4 p = s_p[r];
            const float xi = p.x, yi = p.y, zi = p.z, sqi = p.w;
            const int bi = s_b[r];
            float rr[4];
#pragma unroll
            for (int m = 0; m < 4; m++) {
                float dot = fmaf(zi, zj[m], fmaf(yi, yj[m], __fmul_rn(xi, xj[m])));
                float d2 = __fsub_rn(__fadd_rn(sqi, sqj[m]), __fadd_rn(dot, dot));
                bool v = (d2 < 64.0f) && (bi == bj[m]) && ((i0 + r) != (j0 + m));
                rr[m] = v ? 1.0f : 0.0f;
            }
            vf4 rv = {rr[0], rr[1], rr[2], rr[3]};
            *(vf4*)(adj + (size_t)(i0 + r) * N_NODES + j0) = rv;
        }
    }
}

extern "C" void kernel_launch(void* const* d_in, const int* in_sizes, int n_in,
                              void* d_out, int out_size, void* d_ws, size_t ws_size,
                              hipStream_t stream) {
    const int*   z     = (const int*)d_in[0];
    const void*  batch = d_in[1];           // int32 or int64, detected at runtime
    const float* pos   = (const float*)d_in[2];
    const float* emb   = (const float*)d_in[3];
    const float* w1    = (const float*)d_in[4];
    const float* b1    = (const float*)d_in[5];
    const float* w2    = (const float*)d_in[6];
    const float* b2    = (const float*)d_in[7];

    float* out = (float*)d_out;             // [16384] node outputs
    float* adj = out + N_NODES;             // [16384 x 16384] adjacency as 0/1 floats
    int* ws = (int*)d_ws;                   // ws[0]=dtype flag, ws[1..65]=batch CSR

    mlp_kernel<<<N_NODES / 4, 256, 0, stream>>>(z, emb, w1, b1, w2, b2,
                                                (const int*)batch, ws, out);
    zero_kernel<<<ZBLOCKS, 256, 0, stream>>>(adj);
    window_kernel<<<N_NODES / TI, 256, 0, stream>>>(pos, batch, ws, adj);
}

// Round 3
// 1063.147 us; speedup vs baseline: 1.0759x; 1.0701x over previous
//
#include <hip/hip_runtime.h>
#include <math.h>

#define N_NODES 16384
#define TI 8                 // rows per window-compute block (one batch-window stripe)

typedef float vf4 __attribute__((ext_vector_type(4)));

// ---------------------------------------------------------------------------
// MLP: out[i] = silu(emb[z[i]] @ w1 + b1) @ w2 + b2
// One wave (64 lanes) per node; lane j owns column j of w1 (128x64).
//
// Block 0 additionally:
//  (a) detects whether `batch` is int64 (jax x64) or int32: batch is sorted
//      non-decreasing in [0,64). Read as int32: the int32 case never
//      decreases; the int64 case interleaves zeros -> decreases appear.
//      ws[0] = flag (0 = int32, 1 = int64).
//  (b) builds a batch-CSR: ws[1+v] = first index j with batch[j] >= v, for
//      v = 0..64 (so ws[65] == N). Sorted batch => the candidate columns for
//      a row with batch value b are exactly [ws[1+b], ws[2+b]).
// Consumed by window_kernel (same stream => ordered at kernel boundary).
// ---------------------------------------------------------------------------
__global__ __launch_bounds__(256) void mlp_kernel(const int* __restrict__ z,
                                                  const float* __restrict__ emb,
                                                  const float* __restrict__ w1,
                                                  const float* __restrict__ b1,
                                                  const float* __restrict__ w2,
                                                  const float* __restrict__ b2,
                                                  const int* __restrict__ batch32,
                                                  int* __restrict__ ws,
                                                  float* __restrict__ out) {
    if (blockIdx.x == 0) {
        __shared__ int dec;
        if (threadIdx.x == 0) dec = 0;
        __syncthreads();
        int local = 0;
        for (int k = threadIdx.x; k < N_NODES - 1; k += 256)
            if (batch32[k + 1] < batch32[k]) local = 1;
        if (local) atomicOr(&dec, 1);
        __syncthreads();
        const bool is64 = (dec != 0);
        const long long* b64v = (const long long*)batch32;
        if (threadIdx.x < 65) {
            const int v = threadIdx.x;
            int lo = 0, hi = N_NODES;
            while (lo < hi) {
                int mid = (lo + hi) >> 1;
                int bm = is64 ? (int)b64v[mid] : batch32[mid];
                if (bm < v) lo = mid + 1; else hi = mid;
            }
            ws[1 + v] = lo;
        }
        if (threadIdx.x == 0) ws[0] = dec;
    }

    const int lane = threadIdx.x & 63;
    const int wave = threadIdx.x >> 6;
    const int i = blockIdx.x * 4 + wave;
    if (i >= N_NODES) return;

    const float4* erow = (const float4*)(emb + (size_t)z[i] * 128);
    float acc = b1[lane];
#pragma unroll 8
    for (int k4 = 0; k4 < 32; k4++) {
        float4 e = erow[k4];
        int k = k4 * 4;
        acc = fmaf(e.x, w1[(k + 0) * 64 + lane], acc);
        acc = fmaf(e.y, w1[(k + 1) * 64 + lane], acc);
        acc = fmaf(e.z, w1[(k + 2) * 64 + lane], acc);
        acc = fmaf(e.w, w1[(k + 3) * 64 + lane], acc);
    }
    float h = acc / (1.0f + expf(-acc));   // silu
    float t = h * w2[lane];
#pragma unroll
    for (int off = 32; off >= 1; off >>= 1)
        t += __shfl_xor(t, off, 64);
    if (lane == 0) out[i] = t + b2[0];
}

// ---------------------------------------------------------------------------
// Window pass: adj[i,j] = (d2 < 64) && (batch[i]==batch[j]) && (i != j).
// The bulk zeroing is done by hipMemsetAsync (the rocclr fillBufferAligned
// kernel itself — counter-verified at 6.25 TB/s). This kernel overwrites
// only the candidate window: each block owns TI=8 rows; batch sorted =>
// candidates are exactly columns [ws[1+batch[i0]], ws[2+batch[i0+TI-1]]).
// Columns widened into the chunk window get 0 via the batch-equality check,
// so the overwrite is exact.
//
// d2 replicates numpy f32 semantics EXACTLY (unchanged from absmax=0 kernel):
//   sq[i]  = rn(rn(x*x + y*y) + z*z)            (elementwise mul, pairwise add)
//   dot    = fma(z,z', fma(y,y', rn(x*x')))     (BLAS sgemm sequential-FMA)
//   d2     = rn(rn(sq_i + sq_j) - 2*dot)
// ---------------------------------------------------------------------------
__global__ __launch_bounds__(256) void window_kernel(const float* __restrict__ pos,
                                                     const void* __restrict__ batch_raw,
                                                     const int* __restrict__ ws,
                                                     float* __restrict__ adj) {
    __shared__ vf4 s_p[TI];
    __shared__ int s_b[TI];

    const bool is64 = (ws[0] != 0);
    const int* b32 = (const int*)batch_raw;
    const long long* b64 = (const long long*)batch_raw;

    const int t  = threadIdx.x;
    const int i0 = blockIdx.x * TI;

    const int b_lo = is64 ? (int)b64[i0] : b32[i0];
    const int b_hi = is64 ? (int)b64[i0 + TI - 1] : b32[i0 + TI - 1];

    const int jlo = ws[1 + b_lo];   // first col with batch >= b_lo
    const int jhi = ws[2 + b_hi];   // first col with batch >  b_hi
    const int clo = jlo >> 2;
    const int chi = (jhi + 3) >> 2;

    if (t < TI) {
        const int i = i0 + t;
        float x = pos[i * 3 + 0], y = pos[i * 3 + 1], z = pos[i * 3 + 2];
        vf4 p;
        p.x = x; p.y = y; p.z = z;
        p.w = __fadd_rn(__fadd_rn(__fmul_rn(x, x), __fmul_rn(y, y)), __fmul_rn(z, z));
        s_p[t] = p;
        s_b[t] = is64 ? (int)b64[i] : b32[i];
    }
    __syncthreads();

    for (int c = clo + t; c < chi; c += 256) {
        const int j0 = c * 4;
        // 4 consecutive j: 12 contiguous floats -> 3 aligned float4 loads.
        const float4* p4 = (const float4*)pos;
        float4 A = p4[c * 3 + 0];
        float4 B = p4[c * 3 + 1];
        float4 C = p4[c * 3 + 2];
        const float xj[4] = {A.x, A.w, B.z, C.y};
        const float yj[4] = {A.y, B.x, B.w, C.z};
        const float zj[4] = {A.z, B.y, C.x, C.w};

        float sqj[4];
#pragma unroll
        for (int m = 0; m < 4; m++)
            sqj[m] = __fadd_rn(__fadd_rn(__fmul_rn(xj[m], xj[m]), __fmul_rn(yj[m], yj[m])),
                               __fmul_rn(zj[m], zj[m]));

        int bj[4];
        if (is64) {
#pragma unroll
            for (int m = 0; m < 4; m++) bj[m] = (int)b64[j0 + m];
        } else {
            int4 bb = *(const int4*)(b32 + j0);
            bj[0] = bb.x; bj[1] = bb.y; bj[2] = bb.z; bj[3] = bb.w;
        }

#pragma unroll
        for (int r = 0; r < TI; r++) {
            vf4 p = s_p[r];
            const float xi = p.x, yi = p.y, zi = p.z, sqi = p.w;
            const int bi = s_b[r];
            float rr[4];
#pragma unroll
            for (int m = 0; m < 4; m++) {
                float dot = fmaf(zi, zj[m], fmaf(yi, yj[m], __fmul_rn(xi, xj[m])));
                float d2 = __fsub_rn(__fadd_rn(sqi, sqj[m]), __fadd_rn(dot, dot));
                bool v = (d2 < 64.0f) && (bi == bj[m]) && ((i0 + r) != (j0 + m));
                rr[m] = v ? 1.0f : 0.0f;
            }
            vf4 rv = {rr[0], rr[1], rr[2], rr[3]};
            *(vf4*)(adj + (size_t)(i0 + r) * N_NODES + j0) = rv;
        }
    }
}

extern "C" void kernel_launch(void* const* d_in, const int* in_sizes, int n_in,
                              void* d_out, int out_size, void* d_ws, size_t ws_size,
                              hipStream_t stream) {
    const int*   z     = (const int*)d_in[0];
    const void*  batch = d_in[1];           // int32 or int64, detected at runtime
    const float* pos   = (const float*)d_in[2];
    const float* emb   = (const float*)d_in[3];
    const float* w1    = (const float*)d_in[4];
    const float* b1    = (const float*)d_in[5];
    const float* w2    = (const float*)d_in[6];
    const float* b2    = (const float*)d_in[7];

    float* out = (float*)d_out;             // [16384] node outputs
    float* adj = out + N_NODES;             // [16384 x 16384] adjacency as 0/1 floats
    int* ws = (int*)d_ws;                   // ws[0]=dtype flag, ws[1..65]=batch CSR

    // 1) MLP + CSR build (writes out[0..N), ws[0..66)); disjoint from adj.
    mlp_kernel<<<N_NODES / 4, 256, 0, stream>>>(z, emb, w1, b1, w2, b2,
                                                (const int*)batch, ws, out);
    // 2) Bulk-zero adj with the rocclr fill kernel itself (proven 6.25 TB/s,
    //    graph-capture legal — the harness's own reset() uses it).
    hipMemsetAsync((void*)adj, 0, (size_t)N_NODES * N_NODES * sizeof(float), stream);
    // 3) Overwrite the ~1.6% candidate window with exact-semantics values.
    window_kernel<<<N_NODES / TI, 256, 0, stream>>>(pos, batch, ws, adj);
}